// Round 5
// baseline (344.666 us; speedup 1.0000x reference)
//
#include <hip/hip_runtime.h>

// MPNN regression. R5: GEMM tile 128x128 -> 64x64 (R4 counters: Occupancy 10%,
// MfmaUtil 7.5% -> latency-bound at 1.2 waves/SIMD; 316 blocks was starving
// the 1024-SIMD chip). Now 1256 blocks, ~4.9 waves/SIMD. fp16 MFMA, f32 acc.

typedef _Float16 half8 __attribute__((ext_vector_type(8)));
typedef float float4v __attribute__((ext_vector_type(4)));

#define ASYNC_COPY16(gptr, lptr)                                              \
    __builtin_amdgcn_global_load_lds(                                         \
        (const __attribute__((address_space(1))) void*)(gptr),                \
        (__attribute__((address_space(3))) void*)(lptr), 16, 0, 0)

// ---------------- fp16 MFMA GEMM ----------------
// C[M,512] = act( A1@W1 [+ A2@W2] + bias ), A row-major fp16 [M,K],
// Wt row-major fp16 [512, ldw] (W transposed; k-offset pre-applied by caller).
// Block tile 64x64, 4 waves of 32x32, BK=64.
__global__ __launch_bounds__(256) void gemm_f16(
    const _Float16* __restrict__ A1, const _Float16* __restrict__ W1t,
    int ldw1, int K1,
    const _Float16* __restrict__ A2, const _Float16* __restrict__ W2t,
    int ldw2, int K2,
    const float* __restrict__ bias, _Float16* __restrict__ C,
    int M, int do_relu)
{
    // [chunk 0..7][row 0..63][8 halves]; chunk ch covers k = ch*8..ch*8+7. 8 KB.
    __shared__ _Float16 As[8 * 64 * 8];
    __shared__ _Float16 Bs[8 * 64 * 8];

    const int tid  = threadIdx.x;
    const int wave = tid >> 6, lane = tid & 63;
    const int bm = blockIdx.x * 64, bn = blockIdx.y * 64;
    const int wr = (wave >> 1) * 32, wc = (wave & 1) * 32;
    const int m16 = lane & 15, quad = lane >> 4;

    float4v acc[2][2] = {};

    float bv[2];
    #pragma unroll
    for (int j = 0; j < 2; ++j) bv[j] = bias[bn + wc + j * 16 + m16];

    // staging row for this thread: row = lane (all t), chunk = t*4 + wave
    int arow = bm + lane; arow = arow < M ? arow : M - 1;
    const int brow = bn + lane;

    for (int pass = 0; pass < 2; ++pass) {
        const _Float16* __restrict__ A  = pass ? A2 : A1;
        const _Float16* __restrict__ Wt = pass ? W2t : W1t;
        const int ldw = pass ? ldw2 : ldw1;
        const int K   = pass ? K2 : K1;
        if (A == nullptr) continue;  // block-uniform

        for (int k0 = 0; k0 < K; k0 += 64) {
            // stage 64 rows x 64 k of A and B: 2 async16 each per thread.
            // slot (t,wave,lane): chunk = t*4+wave, row = lane;
            // LDS dest = wave-uniform base + lane*16 (HW rule).
            #pragma unroll
            for (int t = 0; t < 2; ++t) {
                const int ch = t * 4 + wave;
                ASYNC_COPY16(A + (size_t)arow * K + k0 + ch * 8,
                             (char*)As + (size_t)(ch * 64) * 16);
                ASYNC_COPY16(Wt + (size_t)brow * ldw + k0 + ch * 8,
                             (char*)Bs + (size_t)(ch * 64) * 16);
            }
            __syncthreads();  // drains vmcnt (global_load_lds) + barrier

            #pragma unroll
            for (int c = 0; c < 2; ++c) {   // two 32-wide k groups
                half8 af[2], bf[2];
                #pragma unroll
                for (int i = 0; i < 2; ++i)
                    af[i] = *(const half8*)
                        &As[(size_t)((c * 4 + quad) * 64 + wr + i * 16 + m16) * 8];
                #pragma unroll
                for (int j = 0; j < 2; ++j)
                    bf[j] = *(const half8*)
                        &Bs[(size_t)((c * 4 + quad) * 64 + wc + j * 16 + m16) * 8];
                #pragma unroll
                for (int i = 0; i < 2; ++i)
                    #pragma unroll
                    for (int j = 0; j < 2; ++j)
                        acc[i][j] = __builtin_amdgcn_mfma_f32_16x16x32_f16(
                            af[i], bf[j], acc[i][j], 0, 0, 0);
            }
            __syncthreads();
        }
    }

    // epilogue: D layout col=lane&15, row=quad*4+reg
    #pragma unroll
    for (int i = 0; i < 2; ++i) {
        #pragma unroll
        for (int rg = 0; rg < 4; ++rg) {
            const int row = bm + wr + i * 16 + quad * 4 + rg;
            if (row >= M) continue;
            #pragma unroll
            for (int j = 0; j < 2; ++j) {
                float v = acc[i][j][rg] + bv[j];
                if (do_relu) v = fmaxf(v, 0.f);
                C[(size_t)row * 512 + bn + wc + j * 16 + m16] = (_Float16)v;
            }
        }
    }
}

// ---------------- fused prep: weight transposes + x cast + deg zero ----------
// All weight matrices are [R,512] f32 -> dst [512,R] fp16. Tile = 32x32.
__global__ __launch_bounds__(256) void prep(
    const float* __restrict__ W_in,  _Float16* __restrict__ WinT,
    const float* __restrict__ msg_W, _Float16* __restrict__ msgT,
    const float* __restrict__ upd_W, _Float16* __restrict__ updT,
    const float* __restrict__ x,     _Float16* __restrict__ xb,
    int* __restrict__ deg, int n4, int M)
{
    const int b = blockIdx.x;
    const int tid = threadIdx.x;
    if (b < 1664) {
        const float* src; _Float16* dst; int R; int tb;
        if (b < 128)       { src = W_in;               dst = WinT;               R = 256;  tb = b; }
        else if (b < 384)  { src = msg_W;              dst = msgT;               R = 512;  tb = b - 128; }
        else if (b < 640)  { src = msg_W + 512 * 512;  dst = msgT + 512 * 512;   R = 512;  tb = b - 384; }
        else if (b < 1152) { src = upd_W;              dst = updT;               R = 1024; tb = b - 640; }
        else               { src = upd_W + 1024 * 512; dst = updT + 1024 * 512;  R = 1024; tb = b - 1152; }
        const int rtiles = R >> 5;
        const int r0 = (tb % rtiles) * 32;
        const int c0 = (tb / rtiles) * 32;
        __shared__ float t[32][33];
        const int tx = tid & 31, ty = tid >> 5;  // ty 0..7
        #pragma unroll
        for (int i = 0; i < 32; i += 8)
            t[ty + i][tx] = src[(size_t)(r0 + ty + i) * 512 + c0 + tx];
        __syncthreads();
        #pragma unroll
        for (int i = 0; i < 32; i += 8)
            dst[(size_t)(c0 + ty + i) * R + r0 + tx] = (_Float16)t[tx][ty + i];
    } else {
        const int cb = b - 1664;
        const int i = cb * 256 + tid;
        if (i < n4) {
            const float4 v = *(const float4*)(x + (size_t)i * 4);
            ushort4 s;
            union { _Float16 h; unsigned short u; } cv;
            cv.h = (_Float16)v.x; s.x = cv.u;
            cv.h = (_Float16)v.y; s.y = cv.u;
            cv.h = (_Float16)v.z; s.z = cv.u;
            cv.h = (_Float16)v.w; s.w = cv.u;
            *(ushort4*)((unsigned short*)xb + (size_t)i * 4) = s;
        }
        const int castBlocks = (n4 + 255) / 256;
        if (cb >= castBlocks) {
            const int zi = (cb - castBlocks) * 256 + tid;
            if (zi < M) deg[zi] = 0;
        }
    }
}

// ---------------- CSR build ----------------
__global__ __launch_bounds__(256) void count_deg(
    const int* __restrict__ eidx, int* __restrict__ deg, int E)
{
    const int e = blockIdx.x * 256 + threadIdx.x;
    if (e < E) atomicAdd(&deg[eidx[E + e]], 1);
}

__global__ __launch_bounds__(256) void scan_offsets(
    const int* __restrict__ deg, int* __restrict__ offs,
    int* __restrict__ cursor, int n)
{
    __shared__ int part[256];
    const int tid = threadIdx.x;
    const int chunk = (n + 255) / 256;
    const int base = tid * chunk;
    int sum = 0;
    for (int i = 0; i < chunk; ++i) {
        const int idx = base + i;
        if (idx < n) sum += deg[idx];
    }
    part[tid] = sum;
    __syncthreads();
    for (int off = 1; off < 256; off <<= 1) {
        const int v = (tid >= off) ? part[tid - off] : 0;
        __syncthreads();
        part[tid] += v;
        __syncthreads();
    }
    int run = (tid == 0) ? 0 : part[tid - 1];
    for (int i = 0; i < chunk; ++i) {
        const int idx = base + i;
        if (idx < n) { offs[idx] = run; cursor[idx] = run; run += deg[idx]; }
    }
    if (tid == 255) offs[n] = part[255];
}

__global__ __launch_bounds__(256) void fill_csr(
    const int* __restrict__ eidx, int* __restrict__ cursor,
    int* __restrict__ srcs, int E)
{
    const int e = blockIdx.x * 256 + threadIdx.x;
    if (e < E) {
        const int pos = atomicAdd(&cursor[eidx[E + e]], 1);
        srcs[pos] = eidx[e];
    }
}

// ---------------- aggregation: aggr[d] = sum hmr[src] (fp16 in/out, f32 acc) --
__global__ __launch_bounds__(256) void aggregate_f16(
    const _Float16* __restrict__ hmr, const int* __restrict__ offs,
    const int* __restrict__ srcs, _Float16* __restrict__ aggr, int n)
{
    const int t = blockIdx.x * 256 + threadIdx.x;
    const int node = t >> 6;
    if (node >= n) return;
    const int c8 = (t & 63) * 8;
    const int beg = offs[node], end = offs[node + 1];
    float a[8] = {};
    int j = beg;
    for (; j + 1 < end; j += 2) {
        const half8 v0 = *(const half8*)(hmr + (size_t)srcs[j]     * 512 + c8);
        const half8 v1 = *(const half8*)(hmr + (size_t)srcs[j + 1] * 512 + c8);
        #pragma unroll
        for (int i = 0; i < 8; ++i) a[i] += (float)v0[i] + (float)v1[i];
    }
    if (j < end) {
        const half8 v = *(const half8*)(hmr + (size_t)srcs[j] * 512 + c8);
        #pragma unroll
        for (int i = 0; i < 8; ++i) a[i] += (float)v[i];
    }
    half8 o;
    #pragma unroll
    for (int i = 0; i < 8; ++i) o[i] = (_Float16)a[i];
    *(half8*)(aggr + (size_t)node * 512 + c8) = o;
}

// ---------------- epilogue dot: out = h @ W_out + b_out ----------------
__global__ __launch_bounds__(256) void out_dot(
    const _Float16* __restrict__ h, const float* __restrict__ Wout,
    const float* __restrict__ bout, float* __restrict__ out, int M)
{
    const int gid = blockIdx.x * 256 + threadIdx.x;
    const int node = gid >> 6;
    const int lane = gid & 63;
    if (node >= M) return;
    const half8 hv = *(const half8*)(h + (size_t)node * 512 + lane * 8);
    const float4 w0 = *(const float4*)(Wout + lane * 8);
    const float4 w1 = *(const float4*)(Wout + lane * 8 + 4);
    float s = (float)hv[0] * w0.x + (float)hv[1] * w0.y
            + (float)hv[2] * w0.z + (float)hv[3] * w0.w
            + (float)hv[4] * w1.x + (float)hv[5] * w1.y
            + (float)hv[6] * w1.z + (float)hv[7] * w1.w;
    #pragma unroll
    for (int off = 32; off > 0; off >>= 1)
        s += __shfl_down(s, off);
    if (lane == 0) out[node] = s + bout[0];
}

extern "C" void kernel_launch(void* const* d_in, const int* in_sizes, int n_in,
                              void* d_out, int out_size, void* d_ws, size_t ws_size,
                              hipStream_t stream)
{
    const float* x     = (const float*)d_in[0];
    const int*   eidx  = (const int*)  d_in[1];
    const float* W_in  = (const float*)d_in[2];
    const float* b_in  = (const float*)d_in[3];
    const float* msg_W = (const float*)d_in[4];
    const float* msg_b = (const float*)d_in[5];
    const float* upd_W = (const float*)d_in[6];
    const float* upd_b = (const float*)d_in[7];
    const float* W_out = (const float*)d_in[8];
    const float* b_out = (const float*)d_in[9];

    const int IN = 256, H = 512, L = 2;
    const int M = in_sizes[0] / IN;   // 10000
    const int E = in_sizes[1] / 2;    // 160000

    // workspace layout (fp16 chunks all 16B-aligned)
    _Float16* xb   = (_Float16*)d_ws;                 // [M*256]
    _Float16* B0   = xb + (size_t)M * IN;             // [M*512]
    _Float16* B1   = B0 + (size_t)M * H;
    _Float16* B2   = B1 + (size_t)M * H;
    _Float16* WinT = B2 + (size_t)M * H;              // [512,256]
    _Float16* msgT = WinT + (size_t)H * IN;           // [2][512,512]
    _Float16* updT = msgT + (size_t)L * H * H;        // [2][512,1024]
    int* deg    = (int*)(updT + (size_t)L * H * 2 * H);
    int* offs   = deg + M;
    int* cursor = offs + M + 1;
    int* srcs   = cursor + M;

    const dim3 blk(256);
    const dim3 gemmGrid((M + 63) / 64, H / 64);
    const dim3 edgeGrid((E + 255) / 256);

    // one fused prep launch: 5 transposes + x cast + deg zero
    const int n4 = M * IN / 4;
    const int castBlocks = (n4 + 255) / 256;
    const int zeroBlocks = (M + 255) / 256;
    prep<<<dim3(1664 + castBlocks + zeroBlocks), blk, 0, stream>>>(
        W_in, WinT, msg_W, msgT, upd_W, updT, x, xb, deg, n4, M);

    // CSR build (dst buckets), reused for both layers
    count_deg<<<edgeGrid, blk, 0, stream>>>(eidx, deg, E);
    scan_offsets<<<dim3(1), blk, 0, stream>>>(deg, offs, cursor, M);
    fill_csr<<<edgeGrid, blk, 0, stream>>>(eidx, cursor, srcs, E);

    // h0 = relu(x @ W_in + b_in)
    gemm_f16<<<gemmGrid, blk, 0, stream>>>(xb, WinT, IN, IN,
                                           nullptr, nullptr, 0, 0,
                                           b_in, B0, M, 1);

    _Float16* h   = B0;
    _Float16* tmp = B1;
    _Float16* ag  = B2;
    for (int l = 0; l < L; ++l) {
        gemm_f16<<<gemmGrid, blk, 0, stream>>>(
            h, msgT + (size_t)l * H * H, H, H,
            nullptr, nullptr, 0, 0,
            msg_b + (size_t)l * H, tmp, M, 1);
        aggregate_f16<<<dim3((M * 64 + 255) / 256), blk, 0, stream>>>(
            tmp, offs, srcs, ag, M);
        const _Float16* Wu = updT + (size_t)l * H * 2 * H;  // [512,1024]
        gemm_f16<<<gemmGrid, blk, 0, stream>>>(
            h, Wu, 2 * H, H,
            ag, Wu + H, 2 * H, H,      // k-offset 512 within each row
            upd_b + (size_t)l * H, tmp, M, 1);
        _Float16* sw = h; h = tmp; tmp = sw;
    }

    out_dot<<<dim3((M * 64 + 255) / 256), blk, 0, stream>>>(
        h, W_out, b_out, (float*)d_out, M);
}